// Round 1
// baseline (1499.456 us; speedup 1.0000x reference)
//
#include <hip/hip_runtime.h>
#include <math.h>

#define NLEV 8

struct Scales { float s[NLEV]; };

__device__ __forceinline__ float4 enc2d(float pa, float pb, float s,
                                        const float* __restrict__ tbl,
                                        unsigned mask)
{
    float posa = pa * s + 0.5f;
    float posb = pb * s + 0.5f;
    float fla = floorf(posa), flb = floorf(posb);
    float fra = posa - fla, frb = posb - flb;
    unsigned ua = (unsigned)fla, ub = (unsigned)flb;
    float wa0 = 1.0f - fra, wb0 = 1.0f - frb;
    float4 acc = make_float4(0.f, 0.f, 0.f, 0.f);
#pragma unroll
    for (int c = 0; c < 4; ++c) {
        unsigned ca = ua + (c & 1);
        unsigned cb = ub + ((c >> 1) & 1);
        unsigned h = ca ^ (cb * 2654435761u);
        unsigned idx = h & mask;
        float4 v = *reinterpret_cast<const float4*>(tbl + (size_t)idx * 4u);
        float w = ((c & 1) ? fra : wa0) * (((c >> 1) & 1) ? frb : wb0);
        acc.x += w * v.x; acc.y += w * v.y; acc.z += w * v.z; acc.w += w * v.w;
    }
    return acc;
}

__global__ __launch_bounds__(256) void hg4d_kernel(
    const float* __restrict__ x,
    const float* __restrict__ tptr,
    const float* __restrict__ tstat,
    const float* __restrict__ txy,
    const float* __restrict__ txz,
    const float* __restrict__ tyz,
    float* __restrict__ outs,
    float* __restrict__ outd,
    int N, Scales sc)
{
    int n = blockIdx.x * blockDim.x + threadIdx.x;
    if (n >= N) return;
    float x0 = x[3 * (size_t)n + 0];
    float x1 = x[3 * (size_t)n + 1];
    float x2 = x[3 * (size_t)n + 2];
    float t = tptr[0];

    // ---- static 3D hash grid: 8 levels x 8 corners ----
#pragma unroll
    for (int l = 0; l < NLEV; ++l) {
        float s = sc.s[l];
        float p0 = x0 * s + 0.5f, p1 = x1 * s + 0.5f, p2 = x2 * s + 0.5f;
        float q0 = floorf(p0), q1 = floorf(p1), q2 = floorf(p2);
        float f0 = p0 - q0, f1 = p1 - q1, f2 = p2 - q2;
        unsigned u0 = (unsigned)q0, u1 = (unsigned)q1, u2 = (unsigned)q2;
        float g0 = 1.f - f0, g1 = 1.f - f1, g2 = 1.f - f2;
        const float* tb = tstat + (size_t)l * (1u << 19) * 4u;
        float4 acc = make_float4(0.f, 0.f, 0.f, 0.f);
#pragma unroll
        for (int c = 0; c < 8; ++c) {
            unsigned c0 = u0 + (c & 1);
            unsigned c1 = u1 + ((c >> 1) & 1);
            unsigned c2 = u2 + ((c >> 2) & 1);
            unsigned h = c0 ^ (c1 * 2654435761u) ^ (c2 * 805459861u);
            unsigned idx = h & ((1u << 19) - 1u);
            float4 v = *reinterpret_cast<const float4*>(tb + (size_t)idx * 4u);
            float w = ((c & 1) ? f0 : g0) * (((c >> 1) & 1) ? f1 : g1)
                    * (((c >> 2) & 1) ? f2 : g2);
            acc.x += w * v.x; acc.y += w * v.y; acc.z += w * v.z; acc.w += w * v.w;
        }
        *reinterpret_cast<float4*>(outs + (size_t)n * 32u + l * 4u) = acc;
    }

    // ---- dynamic tri-plane, time-blended ----
    float idxf = t * 7.0f;            // t * (TIME_RES - 1)
    float fl = floorf(idxf);
    int i1 = (int)fl;
    int i2 = (int)ceilf(idxf);
    float w2 = idxf - fl;
    float w1 = 1.0f - w2;

    // Lagrange coefficients at Tn = {0, 1/3, 2/3, 1}, sequential like reference
    float Tn[4] = {0.f, 1.f / 3.f, 2.f / 3.f, 1.f};
    float coef[4];
#pragma unroll
    for (int i = 0; i < 4; ++i) {
        float c = 1.0f;
#pragma unroll
        for (int m = 0; m < 4; ++m)
            if (m != i) c = c * (t - Tn[m]) / (Tn[i] - Tn[m]);
        coef[i] = c;
    }

    float od[24];

    auto plane = [&](float pa, float pb, const float* __restrict__ tbl,
                     unsigned Tsz, int ob) {
        const float* b1 = tbl + (size_t)i1 * NLEV * Tsz * 4u;
        const float* b2 = tbl + (size_t)i2 * NLEV * Tsz * 4u;
#pragma unroll
        for (int l = 0; l < NLEV; ++l) {
            float s = sc.s[l];
            const float* t1 = b1 + (size_t)l * Tsz * 4u;
            const float* t2 = b2 + (size_t)l * Tsz * 4u;
            float4 a = enc2d(pa, pb, s, t1, Tsz - 1u);
            float4 b = enc2d(pa, pb, s, t2, Tsz - 1u);
            float bx = w1 * a.x + w2 * b.x;
            float by = w1 * a.y + w2 * b.y;
            float bz = w1 * a.z + w2 * b.z;
            float bw = w1 * a.w + w2 * b.w;
            float o = coef[0] * bx;
            o = o + coef[1] * by;
            o = o + coef[2] * bz;
            o = o + coef[3] * bw;
            od[ob + l] = o;
        }
    };
    plane(x0, x1, txy, 1u << 15, 0);
    plane(x0, x2, txz, 1u << 13, 8);
    plane(x1, x2, tyz, 1u << 13, 16);

    float* op = outd + (size_t)n * 24u;
#pragma unroll
    for (int k = 0; k < 6; ++k) {
        float4 v = make_float4(od[4 * k], od[4 * k + 1], od[4 * k + 2], od[4 * k + 3]);
        *reinterpret_cast<float4*>(op + 4 * k) = v;
    }
}

extern "C" void kernel_launch(void* const* d_in, const int* in_sizes, int n_in,
                              void* d_out, int out_size, void* d_ws, size_t ws_size,
                              hipStream_t stream) {
    const float* x     = (const float*)d_in[0];
    const float* tptr  = (const float*)d_in[1];
    const float* tstat = (const float*)d_in[2];
    const float* txy   = (const float*)d_in[3];
    const float* txz   = (const float*)d_in[4];
    const float* tyz   = (const float*)d_in[5];
    int N = in_sizes[0] / 3;
    float* outs = (float*)d_out;
    float* outd = outs + (size_t)N * 32u;

    Scales sc;
    const double pls = 6.0 / 7.0;  // log2(32768/512) / (8-1)
    for (int l = 0; l < NLEV; ++l)
        sc.s[l] = (float)(exp2((double)l * pls) * 512.0 - 1.0);

    dim3 block(256);
    dim3 grid((N + 255) / 256);
    hipLaunchKernelGGL(hg4d_kernel, grid, block, 0, stream,
                       x, tptr, tstat, txy, txz, tyz, outs, outd, N, sc);
}